// Round 8
// baseline (650.265 us; speedup 1.0000x reference)
//
#include <hip/hip_runtime.h>
#include <math.h>

#define NB 8
#define NC 3
#define NN 4096
#define NK 40
#define NF 64

// ---------------- cross-lane helpers (wave64) ----------------
__device__ __forceinline__ unsigned long long sx64(unsigned long long v, int m) {
  int lo = __shfl_xor((int)(unsigned)v, m, 64);
  int hi = __shfl_xor((int)(v >> 32), m, 64);
  return ((unsigned long long)(unsigned)hi << 32) | (unsigned)lo;
}

// bitonic compare-exchange on u32, descending-final network (vl = lane)
__device__ __forceinline__ void ce32k(unsigned &x, int lane, int k, int j) {
  unsigned o = (unsigned)__shfl_xor((int)x, j, 64);
  const bool tm = ((lane & j) == 0) == ((lane & k) == 0);
  const unsigned mx = x > o ? x : o;
  const unsigned mn = x > o ? o : x;
  x = tm ? mx : mn;
}
// full descending sort of 64 u32 across lanes (21 stages)
__device__ __forceinline__ void sort64_u32(unsigned &x, int lane) {
  #pragma unroll
  for (int k = 2; k <= 64; k <<= 1) {
    #pragma unroll
    for (int j = k >> 1; j >= 1; j >>= 1) ce32k(x, lane, k, j);
  }
}
// a: sorted desc; b: sorted desc. a <- top-64 of (a ∪ b), sorted desc.
__device__ __forceinline__ void merge64_u32(unsigned &a, unsigned b, int lane) {
  unsigned br = (unsigned)__shfl((int)b, 63 - lane, 64);   // reverse -> ascending
  a = a > br ? a : br;                                     // half-cleaner: keep maxes
  #pragma unroll
  for (int j = 32; j >= 1; j >>= 1) {                      // a is bitonic -> desc merge
    unsigned o = (unsigned)__shfl_xor((int)a, j, 64);
    const bool tm = (lane & j) == 0;
    const unsigned mx = a > o ? a : o;
    const unsigned mn = a > o ? o : a;
    a = tm ? mx : mn;
  }
}
// descending sort of 64 u64 keys across lanes (exact re-rank)
__device__ __forceinline__ void ce64k(unsigned long long &x, int lane, int k, int j) {
  unsigned long long o = sx64(x, j);
  const bool tm = ((lane & j) == 0) == ((lane & k) == 0);
  const unsigned long long mx = x > o ? x : o;
  const unsigned long long mn = x > o ? o : x;
  x = tm ? mx : mn;
}
__device__ __forceinline__ void sort64_u64(unsigned long long &x, int lane) {
  #pragma unroll
  for (int k = 2; k <= 64; k <<= 1) {
    #pragma unroll
    for (int j = k >> 1; j >= 1; j >>= 1) ce64k(x, lane, k, j);
  }
}

// ---------------- k0: build xyzs = (x,y,z,|p|^2) ----------------
__global__ __launch_bounds__(256) void k0_prep(const float* __restrict__ x, float4* __restrict__ xyzs) {
  const int i = blockIdx.x * 256 + threadIdx.x;   // 0..32767
  const int b = i >> 12, n = i & 4095;
  const float* xb = x + b * (NC * NN);
  const float a0 = xb[n], a1 = xb[n + NN], a2 = xb[n + 2 * NN];
  const float sq = fmaf(a2, a2, fmaf(a1, a1, a0 * a0));
  xyzs[i] = make_float4(a0, a1, a2, sq);
}

// ---------------- k1: exact KNN top-40, float-compare screen + f64 re-rank ----------------
// 512-thread blocks (8 waves share one point tile -> 16 waves/CU resident).
// grid = NB*64 blocks, 64 queries/block (8/wave, 2 groups of 4); 64-slot buffers,
// merge-before-insert => every merge is exactly one sort64+merge64.
__global__ __launch_bounds__(512) void k1_knn(const float4* __restrict__ xyzs, int* __restrict__ idxo) {
  __shared__ float2 xyl[NN];             // 32 KB
  __shared__ float  zl[NN];              // 16 KB
  __shared__ unsigned kq[8][4][64];      // 8 KB: [wave][query][slot]
  const int tid = threadIdx.x;
  const int b = blockIdx.x >> 6;
  const int blkq = blockIdx.x & 63;
  const int w = tid >> 6, lane = tid & 63;
  for (int i = tid; i < NN; i += 512) {
    const float4 v = xyzs[b * NN + i];
    xyl[i] = make_float2(v.x, v.y);
    zl[i] = v.z;
  }
  __syncthreads();
  const unsigned long long lmask = (1ull << lane) - 1ull;

  #pragma unroll 1
  for (int qg = 0; qg < 2; ++qg) {
    const int q0 = blkq * 64 + w * 8 + qg * 4;     // queries q0..q0+3
    float Qx[4], Qy[4], Qz[4], thrF[4];
    unsigned a_[4];
    int cnt[4];
    #pragma unroll
    for (int j = 0; j < 4; ++j) {
      const float2 t = xyl[q0 + j];
      Qx[j] = t.x; Qy[j] = t.y; Qz[j] = zl[q0 + j];
      a_[j] = 0u;
      thrF[j] = __uint_as_float(0x7F800000u);      // +inf: everything passes initially
      cnt[j] = 0;
    }
    #pragma unroll 1
    for (int m0 = 0; m0 < NN; m0 += 64) {
      const int m = m0 + lane;
      const float2 pxy = xyl[m];
      const float pz = zl[m];
      const unsigned idxbits = (unsigned)(4095 - m);
      #pragma unroll
      for (int j = 0; j < 4; ++j) {
        const float dx = Qx[j] - pxy.x;
        const float dy = Qy[j] - pxy.y;
        const float dz = Qz[j] - pz;
        const float d2 = fmaf(dx, dx, fmaf(dy, dy, dz * dz));
        const bool cand = d2 < thrF[j];            // 1-op screen (superset of key>thr)
        const unsigned long long bal = __ballot(cand);
        if (bal) {
          const int npass = __popcll(bal);
          if (cnt[j] + npass > 64) {               // merge BEFORE insert; cnt<=64 entries
            unsigned bb = (lane < cnt[j]) ? kq[w][j][lane] : 0u;
            sort64_u32(bb, lane);
            merge64_u32(a_[j], bb, lane);
            cnt[j] = 0;
            const unsigned thr_key = (unsigned)__shfl((int)a_[j], 63, 64);
            // pass iff quantized d2 <= quantized d2 of 64th: u < (u64&~0xFFF)+0x1000
            thrF[j] = __uint_as_float((~thr_key & 0xFFFFF000u) + 0x1000u);
          }
          const int rank = __popcll(bal & lmask);
          if (cand) {
            const unsigned u = __float_as_uint(d2);
            kq[w][j][cnt[j] + rank] = (~u & 0xFFFFF000u) | idxbits;
          }
          cnt[j] += npass;
        }
      }
    }
    // drain + exact f64 re-rank per query
    #pragma unroll
    for (int j = 0; j < 4; ++j) {
      if (cnt[j] > 0) {
        unsigned bb = (lane < cnt[j]) ? kq[w][j][lane] : 0u;
        sort64_u32(bb, lane);
        merge64_u32(a_[j], bb, lane);
      }
      const int m = 4095 - (int)(a_[j] & 0xFFFu);
      const float2 pxy = xyl[m];
      const float pz = zl[m];
      const double dx = (double)Qx[j] - (double)pxy.x;
      const double dy = (double)Qy[j] - (double)pxy.y;
      const double dz = (double)Qz[j] - (double)pz;
      const double d2d = fma(dx, dx, fma(dy, dy, dz * dz));
      const float pd = (float)(-d2d);                 // single rounding from exact
      unsigned u = __float_as_uint(pd);
      u ^= (unsigned)((int)u >> 31) | 0x80000000u;    // order-preserving float->uint
      unsigned long long key = ((unsigned long long)u << 32) | (unsigned)(4095 - m);
      sort64_u64(key, lane);
      if (lane < NK) idxo[(b * NN + q0 + j) * NK + lane] = 4095 - (int)(key & 0xFFFFFFFFull);
    }
  }
}

// ---------------- k2: edge-feature moments (6 sums + 21 upper-tri products) ----------------
__global__ __launch_bounds__(256) void k2_mom(const float4* __restrict__ xyzs, const int* __restrict__ idx,
                                              float* __restrict__ part) {
  const int tid = threadIdx.x;
  const int gid = blockIdx.x * 256 + tid;
  float acc[27];
  #pragma unroll
  for (int j = 0; j < 27; ++j) acc[j] = 0.f;
  for (int i = 0; i < 10; ++i) {
    const int s = gid + i * 131072;          // B*N*K = 1310720 = 131072*10
    const int b = s / 163840;                // N*K
    const int r = s - b * 163840;
    const int n = r / 40;
    const int m = idx[s];
    const float4 ct = xyzs[b * NN + n];
    const float4 nb = xyzs[b * NN + m];
    const float e[6] = {nb.x - ct.x, nb.y - ct.y, nb.z - ct.z, ct.x, ct.y, ct.z};
    int t = 6;
    #pragma unroll
    for (int c = 0; c < 6; ++c) {
      acc[c] += e[c];
      #pragma unroll
      for (int d = c; d < 6; ++d) { acc[t] = fmaf(e[c], e[d], acc[t]); ++t; }
    }
  }
  const int w = tid >> 6, lane = tid & 63;
  __shared__ float red[4][27];
  #pragma unroll
  for (int j = 0; j < 27; ++j) {
    float v = acc[j];
    #pragma unroll
    for (int mm = 1; mm < 64; mm <<= 1) v += __shfl_xor(v, mm, 64);
    if (lane == 0) red[w][j] = v;
  }
  __syncthreads();
  if (tid < 27) part[blockIdx.x * 27 + tid] = red[0][tid] + red[1][tid] + red[2][tid] + red[3][tid];
}

// ---------------- k3: BN1 stats (analytic from moments), fold into W1 ----------------
__global__ void k3_stats1(const float* __restrict__ part, const float* __restrict__ W1,
                          const float* __restrict__ g1, const float* __restrict__ b1,
                          float* __restrict__ s1) {
  __shared__ float S[27];
  const int t = threadIdx.x;
  if (t < 27) {
    double s = 0.0;
    for (int p = 0; p < 512; ++p) s += (double)part[p * 27 + t];
    S[t] = (float)s;
  }
  __syncthreads();
  if (t < 64) {
    const float inv = 1.f / 1310720.f;
    float mu[6];
    #pragma unroll
    for (int c = 0; c < 6; ++c) mu[c] = S[c] * inv;
    float M[6][6];
    int tt = 6;
    #pragma unroll
    for (int c = 0; c < 6; ++c) {
      #pragma unroll
      for (int d = c; d < 6; ++d) { const float v = S[tt] * inv; M[c][d] = v; M[d][c] = v; ++tt; }
    }
    float wv[6];
    #pragma unroll
    for (int c = 0; c < 6; ++c) wv[c] = W1[t * 6 + c];
    float mean = 0.f;
    #pragma unroll
    for (int c = 0; c < 6; ++c) mean = fmaf(wv[c], mu[c], mean);
    float e2 = 0.f;
    #pragma unroll
    for (int c = 0; c < 6; ++c) {
      float rowdot = 0.f;
      #pragma unroll
      for (int d = 0; d < 6; ++d) rowdot = fmaf(wv[d], M[c][d], rowdot);
      e2 = fmaf(wv[c], rowdot, e2);
    }
    const float var = e2 - mean * mean;
    const float aa = g1[t] / sqrtf(var + 1e-5f);
    const float cc = b1[t] - mean * aa;
    #pragma unroll
    for (int c = 0; c < 6; ++c) s1[t * 8 + c] = aa * wv[c];  // pre-folded W1' = a1*W1
    s1[t * 8 + 6] = cc;
    s1[t * 8 + 7] = 0.f;
  }
}

// ---------------- k46: W2 stage. lane=f, wave=2 points x 2 k's (4 cols/iter) ----------------
// MODE 0: stats + raw-y2 max/min -> part, ymax, ymin   (fused path)
// MODE 1: stats only -> part                           (fallback pass 1)
// MODE 2: final using s2 -> out                        (fallback pass 2)
template<int MODE>
__global__ __launch_bounds__(256) void k46(const float4* __restrict__ xyzs, const int* __restrict__ idx,
                                           const float* __restrict__ s1, const float* __restrict__ W2,
                                           const float* __restrict__ s2, float* __restrict__ part,
                                           float* __restrict__ ymax, float* __restrict__ ymin,
                                           float* __restrict__ out) {
  __shared__ float4 w2s[64 * 16];        // W2 rows as XOR-swizzled quads, 16 KB
  __shared__ float zbuf[4][2][4][64];    // [wave][dbuf][col][g], 8 KB
  __shared__ float red[4][128];
  const int tid = threadIdx.x, w = tid >> 6, f = tid & 63;

  // stage W2 into LDS, swizzled: logical quad q of row r -> phys r*16 + (q ^ (r&15))
  {
    const int r = tid >> 2;
    #pragma unroll
    for (int j = 0; j < 4; ++j) {
      const int q = (tid & 3) + j * 4;
      w2s[r * 16 + (q ^ (r & 15))] = ((const float4*)W2)[r * 16 + q];
    }
  }
  __syncthreads();

  const int pA = blockIdx.x * 8 + w * 2;     // two consecutive points per wave
  const int pB = pA + 1;
  const int pbse = pA & ~(NN - 1);           // b*NN
  const float4 ctA = xyzs[pA];
  const float4 ctB = xyzs[pB];
  // per-lane s1 row (lane = feature g for z production)
  const float4 s1v0 = ((const float4*)(s1 + f * 8))[0];   // w0,w1,w2,w3
  const float4 s1v1 = ((const float4*)(s1 + f * 8))[1];   // w4,w5,cc,pad
  float zbaseA = s1v1.z;
  zbaseA = fmaf(s1v0.w, ctA.x, zbaseA);
  zbaseA = fmaf(s1v1.x, ctA.y, zbaseA);
  zbaseA = fmaf(s1v1.y, ctA.z, zbaseA);
  float zbaseB = s1v1.z;
  zbaseB = fmaf(s1v0.w, ctB.x, zbaseB);
  zbaseB = fmaf(s1v1.x, ctB.y, zbaseB);
  zbaseB = fmaf(s1v1.y, ctB.z, zbaseB);
  float aa = 0.f, cc2 = 0.f;
  if (MODE == 2) { aa = s2[2 * f], cc2 = s2[2 * f + 1]; }
  // neighbor ids: lane k holds k-th neighbor id (lanes 0..39)
  const int iaA = (f < NK) ? idx[pA * NK + f] : 0;
  const int iaB = (f < NK) ? idx[pB * NK + f] : 0;
  const int wbase = f * 16;

  float asA = 0.f, aqA = 0.f, mxA = -3.0e38f, mnA = 3.0e38f;
  float asB = 0.f, aqB = 0.f, mxB = -3.0e38f, mnB = 3.0e38f;

  #pragma unroll 1
  for (int it = 0; it < 20; ++it) {
    const int k0 = 2 * it;
    // 4 columns: (A,k0) (A,k0+1) (B,k0) (B,k0+1)
    const int mA0 = __builtin_amdgcn_readlane(iaA, k0);
    const int mA1 = __builtin_amdgcn_readlane(iaA, k0 + 1);
    const int mB0 = __builtin_amdgcn_readlane(iaB, k0);
    const int mB1 = __builtin_amdgcn_readlane(iaB, k0 + 1);
    const float4 nA0 = xyzs[pbse + mA0];     // wave-uniform -> scalar loads
    const float4 nA1 = xyzs[pbse + mA1];
    const float4 nB0 = xyzs[pbse + mB0];
    const float4 nB1 = xyzs[pbse + mB1];
    float zA0 = zbaseA, zA1 = zbaseA, zB0 = zbaseB, zB1 = zbaseB;
    zA0 = fmaf(s1v0.x, nA0.x - ctA.x, zA0);
    zA0 = fmaf(s1v0.y, nA0.y - ctA.y, zA0);
    zA0 = fmaf(s1v0.z, nA0.z - ctA.z, zA0);
    zA0 = fmaxf(zA0, 0.2f * zA0);
    zA1 = fmaf(s1v0.x, nA1.x - ctA.x, zA1);
    zA1 = fmaf(s1v0.y, nA1.y - ctA.y, zA1);
    zA1 = fmaf(s1v0.z, nA1.z - ctA.z, zA1);
    zA1 = fmaxf(zA1, 0.2f * zA1);
    zB0 = fmaf(s1v0.x, nB0.x - ctB.x, zB0);
    zB0 = fmaf(s1v0.y, nB0.y - ctB.y, zB0);
    zB0 = fmaf(s1v0.z, nB0.z - ctB.z, zB0);
    zB0 = fmaxf(zB0, 0.2f * zB0);
    zB1 = fmaf(s1v0.x, nB1.x - ctB.x, zB1);
    zB1 = fmaf(s1v0.y, nB1.y - ctB.y, zB1);
    zB1 = fmaf(s1v0.z, nB1.z - ctB.z, zB1);
    zB1 = fmaxf(zB1, 0.2f * zB1);
    float* zb = &zbuf[w][it & 1][0][0];      // one base; all accesses via const offsets
    zb[f] = zA0;
    zb[64 + f] = zA1;
    zb[128 + f] = zB0;
    zb[192 + f] = zB1;

    float pacc[4][4];
    #pragma unroll
    for (int c = 0; c < 4; ++c) {
      #pragma unroll
      for (int j = 0; j < 4; ++j) pacc[c][j] = 0.f;
    }
    #pragma unroll
    for (int q = 0; q < 16; ++q) {
      const float4 wv = w2s[wbase + (q ^ (f & 15))];
      float4 v[4];
      v[0] = *(const float4*)(zb + q * 4);
      v[1] = *(const float4*)(zb + 64 + q * 4);
      v[2] = *(const float4*)(zb + 128 + q * 4);
      v[3] = *(const float4*)(zb + 192 + q * 4);
      #pragma unroll
      for (int c = 0; c < 4; ++c) {
        pacc[c][0] = fmaf(wv.x, v[c].x, pacc[c][0]);
        pacc[c][1] = fmaf(wv.y, v[c].y, pacc[c][1]);
        pacc[c][2] = fmaf(wv.z, v[c].z, pacc[c][2]);
        pacc[c][3] = fmaf(wv.w, v[c].w, pacc[c][3]);
      }
    }
    const float y2A0 = (pacc[0][0] + pacc[0][1]) + (pacc[0][2] + pacc[0][3]);
    const float y2A1 = (pacc[1][0] + pacc[1][1]) + (pacc[1][2] + pacc[1][3]);
    const float y2B0 = (pacc[2][0] + pacc[2][1]) + (pacc[2][2] + pacc[2][3]);
    const float y2B1 = (pacc[3][0] + pacc[3][1]) + (pacc[3][2] + pacc[3][3]);
    if (MODE == 2) {
      const float tA0 = fmaf(y2A0, aa, cc2);
      const float tA1 = fmaf(y2A1, aa, cc2);
      const float tB0 = fmaf(y2B0, aa, cc2);
      const float tB1 = fmaf(y2B1, aa, cc2);
      mxA = fmaxf(fmaxf(mxA, fmaxf(tA0, 0.2f * tA0)), fmaxf(tA1, 0.2f * tA1));
      mxB = fmaxf(fmaxf(mxB, fmaxf(tB0, 0.2f * tB0)), fmaxf(tB1, 0.2f * tB1));
    } else {
      asA += y2A0; asA += y2A1;
      aqA = fmaf(y2A0, y2A0, aqA); aqA = fmaf(y2A1, y2A1, aqA);
      asB += y2B0; asB += y2B1;
      aqB = fmaf(y2B0, y2B0, aqB); aqB = fmaf(y2B1, y2B1, aqB);
      if (MODE == 0) {
        mxA = fmaxf(fmaxf(mxA, y2A0), y2A1); mnA = fminf(fminf(mnA, y2A0), y2A1);
        mxB = fmaxf(fmaxf(mxB, y2B0), y2B1); mnB = fminf(fminf(mnB, y2B0), y2B1);
      }
    }
  }

  if (MODE == 0) {
    ymax[pA * NF + f] = mxA;                 // [point][f], coalesced
    ymin[pA * NF + f] = mnA;
    ymax[pB * NF + f] = mxB;
    ymin[pB * NF + f] = mnB;
  }
  if (MODE == 2) {
    out[pbse * NF + f * NN + (pA & (NN - 1))] = mxA;   // (b*64+f)*NN + n
    out[pbse * NF + f * NN + (pB & (NN - 1))] = mxB;
  }
  if (MODE != 2) {
    red[w][f] = asA + asB;
    red[w][64 + f] = aqA + aqB;
    __syncthreads();
    if (tid < 128) part[blockIdx.x * 128 + tid] = red[0][tid] + red[1][tid] + red[2][tid] + red[3][tid];
  }
}

// ---------------- k5a: reduce BN2 partials (4096 x 128) -> sums[128] ----------------
__global__ __launch_bounds__(256) void k5a(const float* __restrict__ part, float* __restrict__ sums) {
  const int t = blockIdx.x;         // stat index 0..127
  const int tid = threadIdx.x;
  double s = 0.0;
  for (int p = tid; p < 4096; p += 256) s += (double)part[p * 128 + t];
  __shared__ double sd[256];
  sd[tid] = s;
  __syncthreads();
  for (int st = 128; st > 0; st >>= 1) {
    if (tid < st) sd[tid] += sd[tid + st];
    __syncthreads();
  }
  if (tid == 0) sums[t] = (float)sd[0];
}

// ---------------- k5b: sums -> affine (a2, c2) ----------------
__global__ void k5b(const float* __restrict__ sums, const float* __restrict__ g2,
                    const float* __restrict__ b2, float* __restrict__ s2) {
  const int t = threadIdx.x;  // 64
  const float inv = 1.f / 1310720.f;
  const float mean = sums[t] * inv;
  const float var = sums[t + 64] * inv - mean * mean;
  const float aa = g2[t] / sqrtf(var + 1e-5f);
  s2[2 * t] = aa;
  s2[2 * t + 1] = b2[t] - mean * aa;
}

// ---------------- k7: affine+lrelu on proper extreme, with LDS tile transpose ----------------
// max_k lrelu(a*y+c) == lrelu(a*max_k y + c) if a>=0 else lrelu(a*min_k y + c)
__global__ __launch_bounds__(256) void k7_apply(const float* __restrict__ ymax, const float* __restrict__ ymin,
                                                const float* __restrict__ s2, float* __restrict__ out) {
  __shared__ float tile[64][65];
  const int blk = blockIdx.x;                 // 0..511
  const int b = blk >> 6, n0 = (blk & 63) * 64;
  const int tid = threadIdx.x;
  const int fr = tid & 63;
  const float aa = s2[2 * fr], cc = s2[2 * fr + 1];
  const bool useMax = (aa >= 0.f);
  #pragma unroll
  for (int it = 0; it < 16; ++it) {
    const int nl = it * 4 + (tid >> 6);
    const int gi = ((b * NN + n0 + nl) << 6) + fr;     // [point][f]
    const float v = useMax ? ymax[gi] : ymin[gi];
    const float t0 = fmaf(aa, v, cc);
    tile[fr][nl] = fmaxf(t0, 0.2f * t0);
  }
  __syncthreads();
  #pragma unroll
  for (int it = 0; it < 16; ++it) {
    const int fw = it * 4 + (tid >> 6);
    const int nl = tid & 63;
    out[(b * NF + fw) * NN + n0 + nl] = tile[fw][nl];  // coalesced
  }
}

extern "C" void kernel_launch(void* const* d_in, const int* in_sizes, int n_in,
                              void* d_out, int out_size, void* d_ws, size_t ws_size,
                              hipStream_t stream) {
  const float* x  = (const float*)d_in[0];
  const float* W1 = (const float*)d_in[1];
  const float* g1 = (const float*)d_in[2];
  const float* b1 = (const float*)d_in[3];
  const float* W2 = (const float*)d_in[4];
  const float* g2 = (const float*)d_in[5];
  const float* b2 = (const float*)d_in[6];
  float* out = (float*)d_out;
  char* ws = (char*)d_ws;
  // workspace layout (16B-aligned slabs)
  float4* xyzs  = (float4*)ws;                       // 524288 B
  int*    idx   = (int*)(ws + 524288);               // 5242880 B -> end 5767168
  float*  part2 = (float*)(ws + 5767168);            // 55296 B   -> end 5822464
  float*  s1    = (float*)(ws + 5822464);            // 2048 B    -> end 5824512
  float*  part4 = (float*)(ws + 5824512);            // 2097152 B -> end 10018816 (slab kept)
  float*  sums  = (float*)(ws + 10018816);           // 512 B     -> end 10019328
  float*  s2    = (float*)(ws + 10019328);           // 512 B     -> end 10019840
  float*  ymax  = (float*)(ws + 10019840);           // 8388608 B -> end 18408448
  float*  ymin  = (float*)(ws + 18408448);           // 8388608 B -> end 26797056
  const size_t FUSED_NEED = 26797056;                // bytes

  k0_prep<<<128, 256, 0, stream>>>(x, xyzs);
  k1_knn<<<512, 512, 0, stream>>>(xyzs, idx);
  k2_mom<<<512, 256, 0, stream>>>(xyzs, idx, part2);
  k3_stats1<<<1, 64, 0, stream>>>(part2, W1, g1, b1, s1);
  if (ws_size >= FUSED_NEED) {
    k46<0><<<4096, 256, 0, stream>>>(xyzs, idx, s1, W2, s2, part4, ymax, ymin, out);
    k5a<<<128, 256, 0, stream>>>(part4, sums);
    k5b<<<1, 64, 0, stream>>>(sums, g2, b2, s2);
    k7_apply<<<512, 256, 0, stream>>>(ymax, ymin, s2, out);
  } else {
    k46<1><<<4096, 256, 0, stream>>>(xyzs, idx, s1, W2, s2, part4, out, out, out);
    k5a<<<128, 256, 0, stream>>>(part4, sums);
    k5b<<<1, 64, 0, stream>>>(sums, g2, b2, s2);
    k46<2><<<4096, 256, 0, stream>>>(xyzs, idx, s1, W2, s2, part4, out, out, out);
  }
}

// Round 9
// 583.662 us; speedup vs baseline: 1.1141x; 1.1141x over previous
//
#include <hip/hip_runtime.h>
#include <math.h>

#define NB 8
#define NC 3
#define NN 4096
#define NK 40
#define NF 64

// ---------------- cross-lane helpers (wave64) ----------------
__device__ __forceinline__ unsigned long long sx64(unsigned long long v, int m) {
  int lo = __shfl_xor((int)(unsigned)v, m, 64);
  int hi = __shfl_xor((int)(v >> 32), m, 64);
  return ((unsigned long long)(unsigned)hi << 32) | (unsigned)lo;
}

// bitonic compare-exchange on u32, descending-final network (vl = lane)
__device__ __forceinline__ void ce32k(unsigned &x, int lane, int k, int j) {
  unsigned o = (unsigned)__shfl_xor((int)x, j, 64);
  const bool tm = ((lane & j) == 0) == ((lane & k) == 0);
  const unsigned mx = x > o ? x : o;
  const unsigned mn = x > o ? o : x;
  x = tm ? mx : mn;
}
// full descending sort of 64 u32 across lanes (21 stages)
__device__ __forceinline__ void sort64_u32(unsigned &x, int lane) {
  #pragma unroll
  for (int k = 2; k <= 64; k <<= 1) {
    #pragma unroll
    for (int j = k >> 1; j >= 1; j >>= 1) ce32k(x, lane, k, j);
  }
}
// a: sorted desc; b: sorted desc. a <- top-64 of (a ∪ b), sorted desc.
__device__ __forceinline__ void merge64_u32(unsigned &a, unsigned b, int lane) {
  unsigned br = (unsigned)__shfl((int)b, 63 - lane, 64);   // reverse -> ascending
  a = a > br ? a : br;                                     // half-cleaner: keep maxes
  #pragma unroll
  for (int j = 32; j >= 1; j >>= 1) {                      // a is bitonic -> desc merge
    unsigned o = (unsigned)__shfl_xor((int)a, j, 64);
    const bool tm = (lane & j) == 0;
    const unsigned mx = a > o ? a : o;
    const unsigned mn = a > o ? o : a;
    a = tm ? mx : mn;
  }
}
// descending sort of 64 u64 keys across lanes (exact re-rank)
__device__ __forceinline__ void ce64k(unsigned long long &x, int lane, int k, int j) {
  unsigned long long o = sx64(x, j);
  const bool tm = ((lane & j) == 0) == ((lane & k) == 0);
  const unsigned long long mx = x > o ? x : o;
  const unsigned long long mn = x > o ? o : x;
  x = tm ? mx : mn;
}
__device__ __forceinline__ void sort64_u64(unsigned long long &x, int lane) {
  #pragma unroll
  for (int k = 2; k <= 64; k <<= 1) {
    #pragma unroll
    for (int j = k >> 1; j >= 1; j >>= 1) ce64k(x, lane, k, j);
  }
}

// ---------------- k0: build xyzs = (x,y,z,|p|^2) ----------------
__global__ __launch_bounds__(256) void k0_prep(const float* __restrict__ x, float4* __restrict__ xyzs) {
  const int i = blockIdx.x * 256 + threadIdx.x;   // 0..32767
  const int b = i >> 12, n = i & 4095;
  const float* xb = x + b * (NC * NN);
  const float a0 = xb[n], a1 = xb[n + NN], a2 = xb[n + 2 * NN];
  const float sq = fmaf(a2, a2, fmaf(a1, a1, a0 * a0));
  xyzs[i] = make_float4(a0, a1, a2, sq);
}

// ---------------- k1: exact KNN top-40, float-compare screen + f64 re-rank ----------------
// 512-thread blocks (8 waves share one point tile -> 16 waves/CU resident).
__global__ __launch_bounds__(512) void k1_knn(const float4* __restrict__ xyzs, int* __restrict__ idxo) {
  __shared__ float2 xyl[NN];             // 32 KB
  __shared__ float  zl[NN];              // 16 KB
  __shared__ unsigned kq[8][4][64];      // 8 KB: [wave][query][slot]
  const int tid = threadIdx.x;
  const int b = blockIdx.x >> 6;
  const int blkq = blockIdx.x & 63;
  const int w = tid >> 6, lane = tid & 63;
  for (int i = tid; i < NN; i += 512) {
    const float4 v = xyzs[b * NN + i];
    xyl[i] = make_float2(v.x, v.y);
    zl[i] = v.z;
  }
  __syncthreads();
  const unsigned long long lmask = (1ull << lane) - 1ull;

  #pragma unroll 1
  for (int qg = 0; qg < 2; ++qg) {
    const int q0 = blkq * 64 + w * 8 + qg * 4;     // queries q0..q0+3
    float Qx[4], Qy[4], Qz[4], thrF[4];
    unsigned a_[4];
    int cnt[4];
    #pragma unroll
    for (int j = 0; j < 4; ++j) {
      const float2 t = xyl[q0 + j];
      Qx[j] = t.x; Qy[j] = t.y; Qz[j] = zl[q0 + j];
      a_[j] = 0u;
      thrF[j] = __uint_as_float(0x7F800000u);      // +inf: everything passes initially
      cnt[j] = 0;
    }
    #pragma unroll 1
    for (int m0 = 0; m0 < NN; m0 += 64) {
      const int m = m0 + lane;
      const float2 pxy = xyl[m];
      const float pz = zl[m];
      const unsigned idxbits = (unsigned)(4095 - m);
      #pragma unroll
      for (int j = 0; j < 4; ++j) {
        const float dx = Qx[j] - pxy.x;
        const float dy = Qy[j] - pxy.y;
        const float dz = Qz[j] - pz;
        const float d2 = fmaf(dx, dx, fmaf(dy, dy, dz * dz));
        const bool cand = d2 < thrF[j];            // 1-op screen (superset of key>thr)
        const unsigned long long bal = __ballot(cand);
        if (bal) {
          const int npass = __popcll(bal);
          if (cnt[j] + npass > 64) {               // merge BEFORE insert; cnt<=64 entries
            unsigned bb = (lane < cnt[j]) ? kq[w][j][lane] : 0u;
            sort64_u32(bb, lane);
            merge64_u32(a_[j], bb, lane);
            cnt[j] = 0;
            const unsigned thr_key = (unsigned)__shfl((int)a_[j], 63, 64);
            // pass iff quantized d2 <= quantized d2 of 64th: u < (u64&~0xFFF)+0x1000
            thrF[j] = __uint_as_float((~thr_key & 0xFFFFF000u) + 0x1000u);
          }
          const int rank = __popcll(bal & lmask);
          if (cand) {
            const unsigned u = __float_as_uint(d2);
            kq[w][j][cnt[j] + rank] = (~u & 0xFFFFF000u) | idxbits;
          }
          cnt[j] += npass;
        }
      }
    }
    // drain + exact f64 re-rank per query
    #pragma unroll
    for (int j = 0; j < 4; ++j) {
      if (cnt[j] > 0) {
        unsigned bb = (lane < cnt[j]) ? kq[w][j][lane] : 0u;
        sort64_u32(bb, lane);
        merge64_u32(a_[j], bb, lane);
      }
      const int m = 4095 - (int)(a_[j] & 0xFFFu);
      const float2 pxy = xyl[m];
      const float pz = zl[m];
      const double dx = (double)Qx[j] - (double)pxy.x;
      const double dy = (double)Qy[j] - (double)pxy.y;
      const double dz = (double)Qz[j] - (double)pz;
      const double d2d = fma(dx, dx, fma(dy, dy, dz * dz));
      const float pd = (float)(-d2d);                 // single rounding from exact
      unsigned u = __float_as_uint(pd);
      u ^= (unsigned)((int)u >> 31) | 0x80000000u;    // order-preserving float->uint
      unsigned long long key = ((unsigned long long)u << 32) | (unsigned)(4095 - m);
      sort64_u64(key, lane);
      if (lane < NK) idxo[(b * NN + q0 + j) * NK + lane] = 4095 - (int)(key & 0xFFFFFFFFull);
    }
  }
}

// ---------------- k2: edge-feature moments (6 sums + 21 upper-tri products) ----------------
__global__ __launch_bounds__(256) void k2_mom(const float4* __restrict__ xyzs, const int* __restrict__ idx,
                                              float* __restrict__ part) {
  const int tid = threadIdx.x;
  const int gid = blockIdx.x * 256 + tid;
  float acc[27];
  #pragma unroll
  for (int j = 0; j < 27; ++j) acc[j] = 0.f;
  for (int i = 0; i < 10; ++i) {
    const int s = gid + i * 131072;          // B*N*K = 1310720 = 131072*10
    const int b = s / 163840;                // N*K
    const int r = s - b * 163840;
    const int n = r / 40;
    const int m = idx[s];
    const float4 ct = xyzs[b * NN + n];
    const float4 nb = xyzs[b * NN + m];
    const float e[6] = {nb.x - ct.x, nb.y - ct.y, nb.z - ct.z, ct.x, ct.y, ct.z};
    int t = 6;
    #pragma unroll
    for (int c = 0; c < 6; ++c) {
      acc[c] += e[c];
      #pragma unroll
      for (int d = c; d < 6; ++d) { acc[t] = fmaf(e[c], e[d], acc[t]); ++t; }
    }
  }
  const int w = tid >> 6, lane = tid & 63;
  __shared__ float red[4][27];
  #pragma unroll
  for (int j = 0; j < 27; ++j) {
    float v = acc[j];
    #pragma unroll
    for (int mm = 1; mm < 64; mm <<= 1) v += __shfl_xor(v, mm, 64);
    if (lane == 0) red[w][j] = v;
  }
  __syncthreads();
  if (tid < 27) part[blockIdx.x * 27 + tid] = red[0][tid] + red[1][tid] + red[2][tid] + red[3][tid];
}

// ---------------- k3: BN1 stats (analytic from moments), fold into W1 ----------------
__global__ void k3_stats1(const float* __restrict__ part, const float* __restrict__ W1,
                          const float* __restrict__ g1, const float* __restrict__ b1,
                          float* __restrict__ s1) {
  __shared__ float S[27];
  const int t = threadIdx.x;
  if (t < 27) {
    double s = 0.0;
    for (int p = 0; p < 512; ++p) s += (double)part[p * 27 + t];
    S[t] = (float)s;
  }
  __syncthreads();
  if (t < 64) {
    const float inv = 1.f / 1310720.f;
    float mu[6];
    #pragma unroll
    for (int c = 0; c < 6; ++c) mu[c] = S[c] * inv;
    float M[6][6];
    int tt = 6;
    #pragma unroll
    for (int c = 0; c < 6; ++c) {
      #pragma unroll
      for (int d = c; d < 6; ++d) { const float v = S[tt] * inv; M[c][d] = v; M[d][c] = v; ++tt; }
    }
    float wv[6];
    #pragma unroll
    for (int c = 0; c < 6; ++c) wv[c] = W1[t * 6 + c];
    float mean = 0.f;
    #pragma unroll
    for (int c = 0; c < 6; ++c) mean = fmaf(wv[c], mu[c], mean);
    float e2 = 0.f;
    #pragma unroll
    for (int c = 0; c < 6; ++c) {
      float rowdot = 0.f;
      #pragma unroll
      for (int d = 0; d < 6; ++d) rowdot = fmaf(wv[d], M[c][d], rowdot);
      e2 = fmaf(wv[c], rowdot, e2);
    }
    const float var = e2 - mean * mean;
    const float aa = g1[t] / sqrtf(var + 1e-5f);
    const float cc = b1[t] - mean * aa;
    #pragma unroll
    for (int c = 0; c < 6; ++c) s1[t * 8 + c] = aa * wv[c];  // pre-folded W1' = a1*W1
    s1[t * 8 + 6] = cc;
    s1[t * 8 + 7] = 0.f;
  }
}

// ---------------- k46: W2 stage. lane=f, wave=2 points, software-pipelined by 1 k-step ----
// iteration k: (1) issue loads for k+1, (2) FMAs on zbuf[k&1] (written last iter),
// (3) compute z(k+1) -> zbuf[(k+1)&1]. Load+LDS latency hides under the FMA loop.
// MODE 0: stats + raw-y2 max/min -> part, ymax, ymin   (fused path)
// MODE 1: stats only -> part                           (fallback pass 1)
// MODE 2: final using s2 -> out                        (fallback pass 2)
template<int MODE>
__global__ __launch_bounds__(256) void k46(const float4* __restrict__ xyzs, const int* __restrict__ idx,
                                           const float* __restrict__ s1, const float* __restrict__ W2,
                                           const float* __restrict__ s2, float* __restrict__ part,
                                           float* __restrict__ ymax, float* __restrict__ ymin,
                                           float* __restrict__ out) {
  __shared__ float4 w2s[64 * 16];        // W2 rows as XOR-swizzled quads, 16 KB
  __shared__ float zbuf[4][2][2][64];    // [wave][dbuf][point][g], 4 KB
  __shared__ float red[4][128];
  const int tid = threadIdx.x, w = tid >> 6, f = tid & 63;

  // stage W2 into LDS, swizzled: logical quad q of row r -> phys r*16 + (q ^ (r&15))
  {
    const int r = tid >> 2;
    #pragma unroll
    for (int j = 0; j < 4; ++j) {
      const int q = (tid & 3) + j * 4;
      w2s[r * 16 + (q ^ (r & 15))] = ((const float4*)W2)[r * 16 + q];
    }
  }
  __syncthreads();

  const int pA = blockIdx.x * 8 + w * 2;     // two consecutive points per wave
  const int pB = pA + 1;
  const int pbse = pA & ~(NN - 1);           // b*NN
  const float4 ctA = xyzs[pA];
  const float4 ctB = xyzs[pB];
  // per-lane s1 row (lane = feature g for z production)
  const float4 s1v0 = ((const float4*)(s1 + f * 8))[0];   // w0,w1,w2,w3
  const float4 s1v1 = ((const float4*)(s1 + f * 8))[1];   // w4,w5,cc,pad
  float zbaseA = s1v1.z;
  zbaseA = fmaf(s1v0.w, ctA.x, zbaseA);
  zbaseA = fmaf(s1v1.x, ctA.y, zbaseA);
  zbaseA = fmaf(s1v1.y, ctA.z, zbaseA);
  float zbaseB = s1v1.z;
  zbaseB = fmaf(s1v0.w, ctB.x, zbaseB);
  zbaseB = fmaf(s1v1.x, ctB.y, zbaseB);
  zbaseB = fmaf(s1v1.y, ctB.z, zbaseB);
  float aa = 0.f, cc2 = 0.f;
  if (MODE == 2) { aa = s2[2 * f], cc2 = s2[2 * f + 1]; }
  // neighbor ids: lane k holds k-th neighbor id (lanes 0..39)
  const int iaA = (f < NK) ? idx[pA * NK + f] : 0;
  const int iaB = (f < NK) ? idx[pB * NK + f] : 0;
  const int wbase = f * 16;

  float asA = 0.f, aqA = 0.f, mxA = -3.0e38f, mnA = 3.0e38f;
  float asB = 0.f, aqB = 0.f, mxB = -3.0e38f, mnB = 3.0e38f;

  // prologue: z(k=0) -> zbuf[0]
  {
    const int mA = __builtin_amdgcn_readlane(iaA, 0);
    const int mB = __builtin_amdgcn_readlane(iaB, 0);
    const float4 nbA = xyzs[pbse + mA];
    const float4 nbB = xyzs[pbse + mB];
    float zA = zbaseA;
    zA = fmaf(s1v0.x, nbA.x - ctA.x, zA);
    zA = fmaf(s1v0.y, nbA.y - ctA.y, zA);
    zA = fmaf(s1v0.z, nbA.z - ctA.z, zA);
    zbuf[w][0][0][f] = fmaxf(zA, 0.2f * zA);
    float zB = zbaseB;
    zB = fmaf(s1v0.x, nbB.x - ctB.x, zB);
    zB = fmaf(s1v0.y, nbB.y - ctB.y, zB);
    zB = fmaf(s1v0.z, nbB.z - ctB.z, zB);
    zbuf[w][0][1][f] = fmaxf(zB, 0.2f * zB);
  }

  #pragma unroll 1
  for (int k = 0; k < NK; ++k) {
    const int d = k & 1;
    // (1) issue next iteration's neighbor loads (wave-uniform -> scalar path)
    float4 nbA = make_float4(0.f, 0.f, 0.f, 0.f);
    float4 nbB = make_float4(0.f, 0.f, 0.f, 0.f);
    if (k < NK - 1) {
      const int mA = __builtin_amdgcn_readlane(iaA, k + 1);
      const int mB = __builtin_amdgcn_readlane(iaB, k + 1);
      nbA = xyzs[pbse + mA];
      nbB = xyzs[pbse + mB];
    }
    // (2) FMA loop on the buffer written LAST iteration (latency already drained)
    float* zAp = &zbuf[w][d][0][0];
    float* zBp = &zbuf[w][d][1][0];
    const float4* qAp = (const float4*)zAp;
    const float4* qBp = (const float4*)zBp;
    float a0 = 0.f, a1 = 0.f, a2 = 0.f, a3 = 0.f;
    float b0 = 0.f, b1 = 0.f, b2 = 0.f, b3 = 0.f;
    #pragma unroll
    for (int q = 0; q < 16; ++q) {
      const float4 wv = w2s[wbase + (q ^ (f & 15))];
      const float4 vA = qAp[q];
      const float4 vB = qBp[q];
      a0 = fmaf(wv.x, vA.x, a0);
      a1 = fmaf(wv.y, vA.y, a1);
      a2 = fmaf(wv.z, vA.z, a2);
      a3 = fmaf(wv.w, vA.w, a3);
      b0 = fmaf(wv.x, vB.x, b0);
      b1 = fmaf(wv.y, vB.y, b1);
      b2 = fmaf(wv.z, vB.z, b2);
      b3 = fmaf(wv.w, vB.w, b3);
    }
    // (3) compute z(k+1), write the other buffer (consumed next iteration)
    if (k < NK - 1) {
      float zA = zbaseA;
      zA = fmaf(s1v0.x, nbA.x - ctA.x, zA);
      zA = fmaf(s1v0.y, nbA.y - ctA.y, zA);
      zA = fmaf(s1v0.z, nbA.z - ctA.z, zA);
      zbuf[w][d ^ 1][0][f] = fmaxf(zA, 0.2f * zA);
      float zB = zbaseB;
      zB = fmaf(s1v0.x, nbB.x - ctB.x, zB);
      zB = fmaf(s1v0.y, nbB.y - ctB.y, zB);
      zB = fmaf(s1v0.z, nbB.z - ctB.z, zB);
      zbuf[w][d ^ 1][1][f] = fmaxf(zB, 0.2f * zB);
    }
    const float y2A = (a0 + a1) + (a2 + a3);
    const float y2B = (b0 + b1) + (b2 + b3);
    if (MODE == 2) {
      const float tA = fmaf(y2A, aa, cc2);
      mxA = fmaxf(mxA, fmaxf(tA, 0.2f * tA));
      const float tB = fmaf(y2B, aa, cc2);
      mxB = fmaxf(mxB, fmaxf(tB, 0.2f * tB));
    } else {
      asA += y2A;
      aqA = fmaf(y2A, y2A, aqA);
      asB += y2B;
      aqB = fmaf(y2B, y2B, aqB);
      if (MODE == 0) {
        mxA = fmaxf(mxA, y2A); mnA = fminf(mnA, y2A);
        mxB = fmaxf(mxB, y2B); mnB = fminf(mnB, y2B);
      }
    }
  }

  if (MODE == 0) {
    ymax[pA * NF + f] = mxA;                 // [point][f], coalesced
    ymin[pA * NF + f] = mnA;
    ymax[pB * NF + f] = mxB;
    ymin[pB * NF + f] = mnB;
  }
  if (MODE == 2) {
    out[pbse * NF + f * NN + (pA & (NN - 1))] = mxA;   // (b*64+f)*NN + n
    out[pbse * NF + f * NN + (pB & (NN - 1))] = mxB;
  }
  if (MODE != 2) {
    red[w][f] = asA + asB;
    red[w][64 + f] = aqA + aqB;
    __syncthreads();
    if (tid < 128) part[blockIdx.x * 128 + tid] = red[0][tid] + red[1][tid] + red[2][tid] + red[3][tid];
  }
}

// ---------------- k5a: reduce BN2 partials (4096 x 128) -> sums[128] ----------------
__global__ __launch_bounds__(256) void k5a(const float* __restrict__ part, float* __restrict__ sums) {
  const int t = blockIdx.x;         // stat index 0..127
  const int tid = threadIdx.x;
  double s = 0.0;
  for (int p = tid; p < 4096; p += 256) s += (double)part[p * 128 + t];
  __shared__ double sd[256];
  sd[tid] = s;
  __syncthreads();
  for (int st = 128; st > 0; st >>= 1) {
    if (tid < st) sd[tid] += sd[tid + st];
    __syncthreads();
  }
  if (tid == 0) sums[t] = (float)sd[0];
}

// ---------------- k5b: sums -> affine (a2, c2) ----------------
__global__ void k5b(const float* __restrict__ sums, const float* __restrict__ g2,
                    const float* __restrict__ b2, float* __restrict__ s2) {
  const int t = threadIdx.x;  // 64
  const float inv = 1.f / 1310720.f;
  const float mean = sums[t] * inv;
  const float var = sums[t + 64] * inv - mean * mean;
  const float aa = g2[t] / sqrtf(var + 1e-5f);
  s2[2 * t] = aa;
  s2[2 * t + 1] = b2[t] - mean * aa;
}

// ---------------- k7: affine+lrelu on proper extreme, with LDS tile transpose ----------------
// max_k lrelu(a*y+c) == lrelu(a*max_k y + c) if a>=0 else lrelu(a*min_k y + c)
__global__ __launch_bounds__(256) void k7_apply(const float* __restrict__ ymax, const float* __restrict__ ymin,
                                                const float* __restrict__ s2, float* __restrict__ out) {
  __shared__ float tile[64][65];
  const int blk = blockIdx.x;                 // 0..511
  const int b = blk >> 6, n0 = (blk & 63) * 64;
  const int tid = threadIdx.x;
  const int fr = tid & 63;
  const float aa = s2[2 * fr], cc = s2[2 * fr + 1];
  const bool useMax = (aa >= 0.f);
  #pragma unroll
  for (int it = 0; it < 16; ++it) {
    const int nl = it * 4 + (tid >> 6);
    const int gi = ((b * NN + n0 + nl) << 6) + fr;     // [point][f]
    const float v = useMax ? ymax[gi] : ymin[gi];
    const float t0 = fmaf(aa, v, cc);
    tile[fr][nl] = fmaxf(t0, 0.2f * t0);
  }
  __syncthreads();
  #pragma unroll
  for (int it = 0; it < 16; ++it) {
    const int fw = it * 4 + (tid >> 6);
    const int nl = tid & 63;
    out[(b * NF + fw) * NN + n0 + nl] = tile[fw][nl];  // coalesced
  }
}

extern "C" void kernel_launch(void* const* d_in, const int* in_sizes, int n_in,
                              void* d_out, int out_size, void* d_ws, size_t ws_size,
                              hipStream_t stream) {
  const float* x  = (const float*)d_in[0];
  const float* W1 = (const float*)d_in[1];
  const float* g1 = (const float*)d_in[2];
  const float* b1 = (const float*)d_in[3];
  const float* W2 = (const float*)d_in[4];
  const float* g2 = (const float*)d_in[5];
  const float* b2 = (const float*)d_in[6];
  float* out = (float*)d_out;
  char* ws = (char*)d_ws;
  // workspace layout (16B-aligned slabs)
  float4* xyzs  = (float4*)ws;                       // 524288 B
  int*    idx   = (int*)(ws + 524288);               // 5242880 B -> end 5767168
  float*  part2 = (float*)(ws + 5767168);            // 55296 B   -> end 5822464
  float*  s1    = (float*)(ws + 5822464);            // 2048 B    -> end 5824512
  float*  part4 = (float*)(ws + 5824512);            // 2097152 B -> end 10018816 (slab kept)
  float*  sums  = (float*)(ws + 10018816);           // 512 B     -> end 10019328
  float*  s2    = (float*)(ws + 10019328);           // 512 B     -> end 10019840
  float*  ymax  = (float*)(ws + 10019840);           // 8388608 B -> end 18408448
  float*  ymin  = (float*)(ws + 18408448);           // 8388608 B -> end 26797056
  const size_t FUSED_NEED = 26797056;                // bytes

  k0_prep<<<128, 256, 0, stream>>>(x, xyzs);
  k1_knn<<<512, 512, 0, stream>>>(xyzs, idx);
  k2_mom<<<512, 256, 0, stream>>>(xyzs, idx, part2);
  k3_stats1<<<1, 64, 0, stream>>>(part2, W1, g1, b1, s1);
  if (ws_size >= FUSED_NEED) {
    k46<0><<<4096, 256, 0, stream>>>(xyzs, idx, s1, W2, s2, part4, ymax, ymin, out);
    k5a<<<128, 256, 0, stream>>>(part4, sums);
    k5b<<<1, 64, 0, stream>>>(sums, g2, b2, s2);
    k7_apply<<<512, 256, 0, stream>>>(ymax, ymin, s2, out);
  } else {
    k46<1><<<4096, 256, 0, stream>>>(xyzs, idx, s1, W2, s2, part4, out, out, out);
    k5a<<<128, 256, 0, stream>>>(part4, sums);
    k5b<<<1, 64, 0, stream>>>(sums, g2, b2, s2);
    k46<2><<<4096, 256, 0, stream>>>(xyzs, idx, s1, W2, s2, part4, out, out, out);
  }
}

// Round 10
// 536.929 us; speedup vs baseline: 1.2111x; 1.0870x over previous
//
#include <hip/hip_runtime.h>
#include <math.h>

#define NB 8
#define NC 3
#define NN 4096
#define NK 40
#define NF 64

// ---------------- cross-lane helpers (wave64) ----------------
__device__ __forceinline__ unsigned long long sx64(unsigned long long v, int m) {
  int lo = __shfl_xor((int)(unsigned)v, m, 64);
  int hi = __shfl_xor((int)(v >> 32), m, 64);
  return ((unsigned long long)(unsigned)hi << 32) | (unsigned)lo;
}

// bitonic compare-exchange on u32, descending-final network (vl = lane)
__device__ __forceinline__ void ce32k(unsigned &x, int lane, int k, int j) {
  unsigned o = (unsigned)__shfl_xor((int)x, j, 64);
  const bool tm = ((lane & j) == 0) == ((lane & k) == 0);
  const unsigned mx = x > o ? x : o;
  const unsigned mn = x > o ? o : x;
  x = tm ? mx : mn;
}
// full descending sort of 64 u32 across lanes (21 stages)
__device__ __forceinline__ void sort64_u32(unsigned &x, int lane) {
  #pragma unroll
  for (int k = 2; k <= 64; k <<= 1) {
    #pragma unroll
    for (int j = k >> 1; j >= 1; j >>= 1) ce32k(x, lane, k, j);
  }
}
// a: sorted desc; b: sorted desc. a <- top-64 of (a ∪ b), sorted desc.
__device__ __forceinline__ void merge64_u32(unsigned &a, unsigned b, int lane) {
  unsigned br = (unsigned)__shfl((int)b, 63 - lane, 64);   // reverse -> ascending
  a = a > br ? a : br;                                     // half-cleaner: keep maxes
  #pragma unroll
  for (int j = 32; j >= 1; j >>= 1) {                      // a is bitonic -> desc merge
    unsigned o = (unsigned)__shfl_xor((int)a, j, 64);
    const bool tm = (lane & j) == 0;
    const unsigned mx = a > o ? a : o;
    const unsigned mn = a > o ? o : a;
    a = tm ? mx : mn;
  }
}
// descending sort of 64 u64 keys across lanes (exact re-rank)
__device__ __forceinline__ void ce64k(unsigned long long &x, int lane, int k, int j) {
  unsigned long long o = sx64(x, j);
  const bool tm = ((lane & j) == 0) == ((lane & k) == 0);
  const unsigned long long mx = x > o ? x : o;
  const unsigned long long mn = x > o ? o : x;
  x = tm ? mx : mn;
}
__device__ __forceinline__ void sort64_u64(unsigned long long &x, int lane) {
  #pragma unroll
  for (int k = 2; k <= 64; k <<= 1) {
    #pragma unroll
    for (int j = k >> 1; j >= 1; j >>= 1) ce64k(x, lane, k, j);
  }
}

// ---------------- k0: build xyzs = (x,y,z,|p|^2) ----------------
__global__ __launch_bounds__(256) void k0_prep(const float* __restrict__ x, float4* __restrict__ xyzs) {
  const int i = blockIdx.x * 256 + threadIdx.x;   // 0..32767
  const int b = i >> 12, n = i & 4095;
  const float* xb = x + b * (NC * NN);
  const float a0 = xb[n], a1 = xb[n + NN], a2 = xb[n + 2 * NN];
  const float sq = fmaf(a2, a2, fmaf(a1, a1, a0 * a0));
  xyzs[i] = make_float4(a0, a1, a2, sq);
}

// ---------------- k1: exact KNN top-40, float-compare screen + f64 re-rank ----------------
// 512-thread blocks (8 waves share one point tile -> 16 waves/CU resident).
__global__ __launch_bounds__(512) void k1_knn(const float4* __restrict__ xyzs, int* __restrict__ idxo) {
  __shared__ float2 xyl[NN];             // 32 KB
  __shared__ float  zl[NN];              // 16 KB
  __shared__ unsigned kq[8][4][64];      // 8 KB: [wave][query][slot]
  const int tid = threadIdx.x;
  const int b = blockIdx.x >> 6;
  const int blkq = blockIdx.x & 63;
  const int w = tid >> 6, lane = tid & 63;
  for (int i = tid; i < NN; i += 512) {
    const float4 v = xyzs[b * NN + i];
    xyl[i] = make_float2(v.x, v.y);
    zl[i] = v.z;
  }
  __syncthreads();
  const unsigned long long lmask = (1ull << lane) - 1ull;

  #pragma unroll 1
  for (int qg = 0; qg < 2; ++qg) {
    const int q0 = blkq * 64 + w * 8 + qg * 4;     // queries q0..q0+3
    float Qx[4], Qy[4], Qz[4], thrF[4];
    unsigned a_[4];
    int cnt[4];
    #pragma unroll
    for (int j = 0; j < 4; ++j) {
      const float2 t = xyl[q0 + j];
      Qx[j] = t.x; Qy[j] = t.y; Qz[j] = zl[q0 + j];
      a_[j] = 0u;
      thrF[j] = __uint_as_float(0x7F800000u);      // +inf: everything passes initially
      cnt[j] = 0;
    }
    #pragma unroll 1
    for (int m0 = 0; m0 < NN; m0 += 64) {
      const int m = m0 + lane;
      const float2 pxy = xyl[m];
      const float pz = zl[m];
      const unsigned idxbits = (unsigned)(4095 - m);
      #pragma unroll
      for (int j = 0; j < 4; ++j) {
        const float dx = Qx[j] - pxy.x;
        const float dy = Qy[j] - pxy.y;
        const float dz = Qz[j] - pz;
        const float d2 = fmaf(dx, dx, fmaf(dy, dy, dz * dz));
        const bool cand = d2 < thrF[j];            // 1-op screen (superset of key>thr)
        const unsigned long long bal = __ballot(cand);
        if (bal) {
          const int npass = __popcll(bal);
          if (cnt[j] + npass > 64) {               // merge BEFORE insert; cnt<=64 entries
            unsigned bb = (lane < cnt[j]) ? kq[w][j][lane] : 0u;
            sort64_u32(bb, lane);
            merge64_u32(a_[j], bb, lane);
            cnt[j] = 0;
            const unsigned thr_key = (unsigned)__shfl((int)a_[j], 63, 64);
            // pass iff quantized d2 <= quantized d2 of 64th: u < (u64&~0xFFF)+0x1000
            thrF[j] = __uint_as_float((~thr_key & 0xFFFFF000u) + 0x1000u);
          }
          const int rank = __popcll(bal & lmask);
          if (cand) {
            const unsigned u = __float_as_uint(d2);
            kq[w][j][cnt[j] + rank] = (~u & 0xFFFFF000u) | idxbits;
          }
          cnt[j] += npass;
        }
      }
    }
    // drain + exact f64 re-rank per query
    #pragma unroll
    for (int j = 0; j < 4; ++j) {
      if (cnt[j] > 0) {
        unsigned bb = (lane < cnt[j]) ? kq[w][j][lane] : 0u;
        sort64_u32(bb, lane);
        merge64_u32(a_[j], bb, lane);
      }
      const int m = 4095 - (int)(a_[j] & 0xFFFu);
      const float2 pxy = xyl[m];
      const float pz = zl[m];
      const double dx = (double)Qx[j] - (double)pxy.x;
      const double dy = (double)Qy[j] - (double)pxy.y;
      const double dz = (double)Qz[j] - (double)pz;
      const double d2d = fma(dx, dx, fma(dy, dy, dz * dz));
      const float pd = (float)(-d2d);                 // single rounding from exact
      unsigned u = __float_as_uint(pd);
      u ^= (unsigned)((int)u >> 31) | 0x80000000u;    // order-preserving float->uint
      unsigned long long key = ((unsigned long long)u << 32) | (unsigned)(4095 - m);
      sort64_u64(key, lane);
      if (lane < NK) idxo[(b * NN + q0 + j) * NK + lane] = 4095 - (int)(key & 0xFFFFFFFFull);
    }
  }
}

// ---------------- k2: edge-feature moments (6 sums + 21 upper-tri products) ----------------
__global__ __launch_bounds__(256) void k2_mom(const float4* __restrict__ xyzs, const int* __restrict__ idx,
                                              float* __restrict__ part) {
  const int tid = threadIdx.x;
  const int gid = blockIdx.x * 256 + tid;
  float acc[27];
  #pragma unroll
  for (int j = 0; j < 27; ++j) acc[j] = 0.f;
  for (int i = 0; i < 10; ++i) {
    const int s = gid + i * 131072;          // B*N*K = 1310720 = 131072*10
    const int b = s / 163840;                // N*K
    const int r = s - b * 163840;
    const int n = r / 40;
    const int m = idx[s];
    const float4 ct = xyzs[b * NN + n];
    const float4 nb = xyzs[b * NN + m];
    const float e[6] = {nb.x - ct.x, nb.y - ct.y, nb.z - ct.z, ct.x, ct.y, ct.z};
    int t = 6;
    #pragma unroll
    for (int c = 0; c < 6; ++c) {
      acc[c] += e[c];
      #pragma unroll
      for (int d = c; d < 6; ++d) { acc[t] = fmaf(e[c], e[d], acc[t]); ++t; }
    }
  }
  const int w = tid >> 6, lane = tid & 63;
  __shared__ float red[4][27];
  #pragma unroll
  for (int j = 0; j < 27; ++j) {
    float v = acc[j];
    #pragma unroll
    for (int mm = 1; mm < 64; mm <<= 1) v += __shfl_xor(v, mm, 64);
    if (lane == 0) red[w][j] = v;
  }
  __syncthreads();
  if (tid < 27) part[blockIdx.x * 27 + tid] = red[0][tid] + red[1][tid] + red[2][tid] + red[3][tid];
}

// ---------------- k3: BN1 stats (analytic from moments), fold into W1 ----------------
__global__ void k3_stats1(const float* __restrict__ part, const float* __restrict__ W1,
                          const float* __restrict__ g1, const float* __restrict__ b1,
                          float* __restrict__ s1) {
  __shared__ float S[27];
  const int t = threadIdx.x;
  if (t < 27) {
    double s = 0.0;
    for (int p = 0; p < 512; ++p) s += (double)part[p * 27 + t];
    S[t] = (float)s;
  }
  __syncthreads();
  if (t < 64) {
    const float inv = 1.f / 1310720.f;
    float mu[6];
    #pragma unroll
    for (int c = 0; c < 6; ++c) mu[c] = S[c] * inv;
    float M[6][6];
    int tt = 6;
    #pragma unroll
    for (int c = 0; c < 6; ++c) {
      #pragma unroll
      for (int d = c; d < 6; ++d) { const float v = S[tt] * inv; M[c][d] = v; M[d][c] = v; ++tt; }
    }
    float wv[6];
    #pragma unroll
    for (int c = 0; c < 6; ++c) wv[c] = W1[t * 6 + c];
    float mean = 0.f;
    #pragma unroll
    for (int c = 0; c < 6; ++c) mean = fmaf(wv[c], mu[c], mean);
    float e2 = 0.f;
    #pragma unroll
    for (int c = 0; c < 6; ++c) {
      float rowdot = 0.f;
      #pragma unroll
      for (int d = 0; d < 6; ++d) rowdot = fmaf(wv[d], M[c][d], rowdot);
      e2 = fmaf(wv[c], rowdot, e2);
    }
    const float var = e2 - mean * mean;
    const float aa = g1[t] / sqrtf(var + 1e-5f);
    const float cc = b1[t] - mean * aa;
    #pragma unroll
    for (int c = 0; c < 6; ++c) s1[t * 8 + c] = aa * wv[c];  // pre-folded W1' = a1*W1
    s1[t * 8 + 6] = cc;
    s1[t * 8 + 7] = 0.f;
  }
}

// ---------------- k46: W2 stage. lane=f, wave=2 points, 1-step software pipeline ----------
// Center term folded into zbase' (= cc' - s1.xyz . ct) so ct is DEAD inside the k-loop:
// z = zbase' + s1.xyz . nb   (saves ~6 live VGPRs + 6 VALU/k-step; keeps VGPR <= 128)
// MODE 0: stats + raw-y2 max/min -> part, ymax, ymin   (fused path)
// MODE 1: stats only -> part                           (fallback pass 1)
// MODE 2: final using s2 -> out                        (fallback pass 2)
template<int MODE>
__global__ __launch_bounds__(256) void k46(const float4* __restrict__ xyzs, const int* __restrict__ idx,
                                           const float* __restrict__ s1, const float* __restrict__ W2,
                                           const float* __restrict__ s2, float* __restrict__ part,
                                           float* __restrict__ ymax, float* __restrict__ ymin,
                                           float* __restrict__ out) {
  __shared__ float4 w2s[64 * 16];        // W2 rows as XOR-swizzled quads, 16 KB
  __shared__ float zbuf[4][2][2][64];    // [wave][dbuf][point][g], 4 KB
  __shared__ float red[4][128];
  const int tid = threadIdx.x, w = tid >> 6, f = tid & 63;

  // stage W2 into LDS, swizzled: logical quad q of row r -> phys r*16 + (q ^ (r&15))
  {
    const int r = tid >> 2;
    #pragma unroll
    for (int j = 0; j < 4; ++j) {
      const int q = (tid & 3) + j * 4;
      w2s[r * 16 + (q ^ (r & 15))] = ((const float4*)W2)[r * 16 + q];
    }
  }
  __syncthreads();

  const int pA = blockIdx.x * 8 + w * 2;     // two consecutive points per wave
  const int pB = pA + 1;
  const int pbse = pA & ~(NN - 1);           // b*NN
  // per-lane s1 row (lane = feature g for z production)
  const float4 s1v0 = ((const float4*)(s1 + f * 8))[0];   // w0,w1,w2,w3
  const float4 s1v1 = ((const float4*)(s1 + f * 8))[1];   // w4,w5,cc,pad
  float zbA, zbB;
  {
    const float4 ctA = xyzs[pA];
    const float4 ctB = xyzs[pB];
    float z = s1v1.z;
    z = fmaf(s1v0.w, ctA.x, z);
    z = fmaf(s1v1.x, ctA.y, z);
    z = fmaf(s1v1.y, ctA.z, z);
    z = fmaf(-s1v0.x, ctA.x, z);
    z = fmaf(-s1v0.y, ctA.y, z);
    z = fmaf(-s1v0.z, ctA.z, z);
    zbA = z;
    z = s1v1.z;
    z = fmaf(s1v0.w, ctB.x, z);
    z = fmaf(s1v1.x, ctB.y, z);
    z = fmaf(s1v1.y, ctB.z, z);
    z = fmaf(-s1v0.x, ctB.x, z);
    z = fmaf(-s1v0.y, ctB.y, z);
    z = fmaf(-s1v0.z, ctB.z, z);
    zbB = z;
  }
  float aa = 0.f, cc2 = 0.f;
  if (MODE == 2) { aa = s2[2 * f], cc2 = s2[2 * f + 1]; }
  // neighbor ids: lane k holds k-th neighbor id (lanes 0..39)
  const int iaA = (f < NK) ? idx[pA * NK + f] : 0;
  const int iaB = (f < NK) ? idx[pB * NK + f] : 0;
  const int wbase = f * 16;

  float asA = 0.f, aqA = 0.f, mxA = -3.0e38f, mnA = 3.0e38f;
  float asB = 0.f, aqB = 0.f, mxB = -3.0e38f, mnB = 3.0e38f;

  // z(k) from prefetched nb, write buffer D
  #define K46_ZWRITE(D, nA, nB)                                                 \
  {                                                                             \
    float zA = zbA;                                                             \
    zA = fmaf(s1v0.x, (nA).x, zA);                                              \
    zA = fmaf(s1v0.y, (nA).y, zA);                                              \
    zA = fmaf(s1v0.z, (nA).z, zA);                                              \
    zbuf[w][D][0][f] = fmaxf(zA, 0.2f * zA);                                    \
    float zB = zbB;                                                             \
    zB = fmaf(s1v0.x, (nB).x, zB);                                              \
    zB = fmaf(s1v0.y, (nB).y, zB);                                              \
    zB = fmaf(s1v0.z, (nB).z, zB);                                              \
    zbuf[w][D][1][f] = fmaxf(zB, 0.2f * zB);                                    \
  }

  // 16-quad FMA block on buffer D -> y2A, y2B, then stats
  #define K46_FMASTATS(D)                                                       \
  {                                                                             \
    const float* zAp = &zbuf[w][D][0][0];                                       \
    const float* zBp = &zbuf[w][D][1][0];                                       \
    const float4* qAp = (const float4*)zAp;                                     \
    const float4* qBp = (const float4*)zBp;                                     \
    float a0 = 0.f, a1 = 0.f, a2 = 0.f, a3 = 0.f;                               \
    float b0 = 0.f, b1 = 0.f, b2 = 0.f, b3 = 0.f;                               \
    _Pragma("unroll")                                                           \
    for (int q = 0; q < 16; ++q) {                                              \
      const float4 wv = w2s[wbase + (q ^ (f & 15))];                            \
      const float4 vA = qAp[q];                                                 \
      const float4 vB = qBp[q];                                                 \
      a0 = fmaf(wv.x, vA.x, a0);                                                \
      a1 = fmaf(wv.y, vA.y, a1);                                                \
      a2 = fmaf(wv.z, vA.z, a2);                                                \
      a3 = fmaf(wv.w, vA.w, a3);                                                \
      b0 = fmaf(wv.x, vB.x, b0);                                                \
      b1 = fmaf(wv.y, vB.y, b1);                                                \
      b2 = fmaf(wv.z, vB.z, b2);                                                \
      b3 = fmaf(wv.w, vB.w, b3);                                                \
    }                                                                           \
    const float y2A = (a0 + a1) + (a2 + a3);                                    \
    const float y2B = (b0 + b1) + (b2 + b3);                                    \
    if (MODE == 2) {                                                            \
      const float tA = fmaf(y2A, aa, cc2);                                      \
      mxA = fmaxf(mxA, fmaxf(tA, 0.2f * tA));                                   \
      const float tB = fmaf(y2B, aa, cc2);                                      \
      mxB = fmaxf(mxB, fmaxf(tB, 0.2f * tB));                                   \
    } else {                                                                    \
      asA += y2A;                                                               \
      aqA = fmaf(y2A, y2A, aqA);                                                \
      asB += y2B;                                                               \
      aqB = fmaf(y2B, y2B, aqB);                                                \
      if (MODE == 0) {                                                          \
        mxA = fmaxf(mxA, y2A); mnA = fminf(mnA, y2A);                           \
        mxB = fmaxf(mxB, y2B); mnB = fminf(mnB, y2B);                           \
      }                                                                         \
    }                                                                           \
  }

  // prologue: z(0) -> buf 0
  {
    const int mA = __builtin_amdgcn_readlane(iaA, 0);
    const int mB = __builtin_amdgcn_readlane(iaB, 0);
    const float4 nA = xyzs[pbse + mA];
    const float4 nB = xyzs[pbse + mB];
    K46_ZWRITE(0, nA, nB)
  }

  #pragma unroll 1
  for (int k = 0; k < NK - 1; ++k) {
    const int d = k & 1;
    // (1) issue next iteration's neighbor loads (wave-uniform)
    const int mA = __builtin_amdgcn_readlane(iaA, k + 1);
    const int mB = __builtin_amdgcn_readlane(iaB, k + 1);
    const float4 nA = xyzs[pbse + mA];
    const float4 nB = xyzs[pbse + mB];
    // (2) FMAs + stats on the buffer written last iteration
    K46_FMASTATS(d)
    // (3) z(k+1) -> other buffer (consumed next iteration)
    K46_ZWRITE(d ^ 1, nA, nB)
  }
  // epilogue: k = NK-1 sits in buf (NK-1)&1 = 1
  K46_FMASTATS(1)
  #undef K46_ZWRITE
  #undef K46_FMASTATS

  if (MODE == 0) {
    ymax[pA * NF + f] = mxA;                 // [point][f], coalesced
    ymin[pA * NF + f] = mnA;
    ymax[pB * NF + f] = mxB;
    ymin[pB * NF + f] = mnB;
  }
  if (MODE == 2) {
    out[pbse * NF + f * NN + (pA & (NN - 1))] = mxA;   // (b*64+f)*NN + n
    out[pbse * NF + f * NN + (pB & (NN - 1))] = mxB;
  }
  if (MODE != 2) {
    red[w][f] = asA + asB;
    red[w][64 + f] = aqA + aqB;
    __syncthreads();
    if (tid < 128) part[blockIdx.x * 128 + tid] = red[0][tid] + red[1][tid] + red[2][tid] + red[3][tid];
  }
}

// ---------------- k5a: reduce BN2 partials (4096 x 128) -> sums[128] ----------------
__global__ __launch_bounds__(256) void k5a(const float* __restrict__ part, float* __restrict__ sums) {
  const int t = blockIdx.x;         // stat index 0..127
  const int tid = threadIdx.x;
  double s = 0.0;
  for (int p = tid; p < 4096; p += 256) s += (double)part[p * 128 + t];
  __shared__ double sd[256];
  sd[tid] = s;
  __syncthreads();
  for (int st = 128; st > 0; st >>= 1) {
    if (tid < st) sd[tid] += sd[tid + st];
    __syncthreads();
  }
  if (tid == 0) sums[t] = (float)sd[0];
}

// ---------------- k5b: sums -> affine (a2, c2) ----------------
__global__ void k5b(const float* __restrict__ sums, const float* __restrict__ g2,
                    const float* __restrict__ b2, float* __restrict__ s2) {
  const int t = threadIdx.x;  // 64
  const float inv = 1.f / 1310720.f;
  const float mean = sums[t] * inv;
  const float var = sums[t + 64] * inv - mean * mean;
  const float aa = g2[t] / sqrtf(var + 1e-5f);
  s2[2 * t] = aa;
  s2[2 * t + 1] = b2[t] - mean * aa;
}

// ---------------- k7: affine+lrelu on proper extreme, with LDS tile transpose ----------------
// max_k lrelu(a*y+c) == lrelu(a*max_k y + c) if a>=0 else lrelu(a*min_k y + c)
__global__ __launch_bounds__(256) void k7_apply(const float* __restrict__ ymax, const float* __restrict__ ymin,
                                                const float* __restrict__ s2, float* __restrict__ out) {
  __shared__ float tile[64][65];
  const int blk = blockIdx.x;                 // 0..511
  const int b = blk >> 6, n0 = (blk & 63) * 64;
  const int tid = threadIdx.x;
  const int fr = tid & 63;
  const float aa = s2[2 * fr], cc = s2[2 * fr + 1];
  const bool useMax = (aa >= 0.f);
  #pragma unroll
  for (int it = 0; it < 16; ++it) {
    const int nl = it * 4 + (tid >> 6);
    const int gi = ((b * NN + n0 + nl) << 6) + fr;     // [point][f]
    const float v = useMax ? ymax[gi] : ymin[gi];
    const float t0 = fmaf(aa, v, cc);
    tile[fr][nl] = fmaxf(t0, 0.2f * t0);
  }
  __syncthreads();
  #pragma unroll
  for (int it = 0; it < 16; ++it) {
    const int fw = it * 4 + (tid >> 6);
    const int nl = tid & 63;
    out[(b * NF + fw) * NN + n0 + nl] = tile[fw][nl];  // coalesced
  }
}

extern "C" void kernel_launch(void* const* d_in, const int* in_sizes, int n_in,
                              void* d_out, int out_size, void* d_ws, size_t ws_size,
                              hipStream_t stream) {
  const float* x  = (const float*)d_in[0];
  const float* W1 = (const float*)d_in[1];
  const float* g1 = (const float*)d_in[2];
  const float* b1 = (const float*)d_in[3];
  const float* W2 = (const float*)d_in[4];
  const float* g2 = (const float*)d_in[5];
  const float* b2 = (const float*)d_in[6];
  float* out = (float*)d_out;
  char* ws = (char*)d_ws;
  // workspace layout (16B-aligned slabs)
  float4* xyzs  = (float4*)ws;                       // 524288 B
  int*    idx   = (int*)(ws + 524288);               // 5242880 B -> end 5767168
  float*  part2 = (float*)(ws + 5767168);            // 55296 B   -> end 5822464
  float*  s1    = (float*)(ws + 5822464);            // 2048 B    -> end 5824512
  float*  part4 = (float*)(ws + 5824512);            // 2097152 B -> end 10018816 (slab kept)
  float*  sums  = (float*)(ws + 10018816);           // 512 B     -> end 10019328
  float*  s2    = (float*)(ws + 10019328);           // 512 B     -> end 10019840
  float*  ymax  = (float*)(ws + 10019840);           // 8388608 B -> end 18408448
  float*  ymin  = (float*)(ws + 18408448);           // 8388608 B -> end 26797056
  const size_t FUSED_NEED = 26797056;                // bytes

  k0_prep<<<128, 256, 0, stream>>>(x, xyzs);
  k1_knn<<<512, 512, 0, stream>>>(xyzs, idx);
  k2_mom<<<512, 256, 0, stream>>>(xyzs, idx, part2);
  k3_stats1<<<1, 64, 0, stream>>>(part2, W1, g1, b1, s1);
  if (ws_size >= FUSED_NEED) {
    k46<0><<<4096, 256, 0, stream>>>(xyzs, idx, s1, W2, s2, part4, ymax, ymin, out);
    k5a<<<128, 256, 0, stream>>>(part4, sums);
    k5b<<<1, 64, 0, stream>>>(sums, g2, b2, s2);
    k7_apply<<<512, 256, 0, stream>>>(ymax, ymin, s2, out);
  } else {
    k46<1><<<4096, 256, 0, stream>>>(xyzs, idx, s1, W2, s2, part4, out, out, out);
    k5a<<<128, 256, 0, stream>>>(part4, sums);
    k5b<<<1, 64, 0, stream>>>(sums, g2, b2, s2);
    k46<2><<<4096, 256, 0, stream>>>(xyzs, idx, s1, W2, s2, part4, out, out, out);
  }
}